// Round 1
// baseline (9904.440 us; speedup 1.0000x reference)
//
#include <hip/hip_runtime.h>
#include <hip/hip_bf16.h>
#include <hip/hip_fp16.h>

#define NF    15
#define NBF   20
#define TT    1760
#define TS    880
#define EP    64
#define ES    128
#define DF    128
#define H1    384
#define G3    1152
#define INA   896
#define JREP  11

typedef _Float16 h2v __attribute__((ext_vector_type(2)));

__device__ __forceinline__ float sigmf_(float x){ return 1.0f/(1.0f + __expf(-x)); }
__device__ __forceinline__ float tanhf_(float x){ return 2.0f/(1.0f + __expf(-2.0f*x)) - 1.0f; }
__device__ __forceinline__ h2v bc_h2(unsigned u){ return __builtin_bit_cast(h2v, u); }
__device__ __forceinline__ float fdot2_(h2v a, h2v b, float c){
#if __has_builtin(__builtin_amdgcn_fdot2)
  return __builtin_amdgcn_fdot2(a, b, c, false);
#else
  return c + (float)a[0]*(float)b[0] + (float)a[1]*(float)b[1];
#endif
}

// ---------------- frame-rate network: f[64][11][128] ----------------
__global__ __launch_bounds__(128) void k_frame(const float* feat, const int* periods, const float* embp,
   const float* c1w, const float* c1b, const float* c2w, const float* c2b,
   const float* f1w, const float* f1b, const float* f2w, const float* f2b, float* fout)
{
  __shared__ float cat[NF*84];
  __shared__ float x1[13*DF];
  __shared__ float x2[JREP*DF];
  int b = blockIdx.x, tid = threadIdx.x;
  for (int idx = tid; idx < NF*84; idx += 128){
    int j = idx/84, c = idx%84;
    cat[idx] = (c < NBF) ? feat[(b*NF+j)*NBF + c]
                         : embp[periods[b*NF+j]*EP + (c-NBF)];
  }
  __syncthreads();
  int o = tid;
  for (int p = 0; p < 13; ++p){
    float acc = c1b[o];
    for (int kk = 0; kk < 3; ++kk)
      for (int c = 0; c < 84; ++c)
        acc += cat[(p+kk)*84 + c] * c1w[(o*84+c)*3+kk];
    x1[p*DF+o] = tanhf_(acc);
  }
  __syncthreads();
  for (int p = 0; p < JREP; ++p){
    float acc = c2b[o];
    for (int kk = 0; kk < 3; ++kk)
      for (int c = 0; c < DF; ++c)
        acc += x1[(p+kk)*DF+c] * c2w[(o*DF+c)*3+kk];
    x2[p*DF+o] = tanhf_(acc);
  }
  __syncthreads();
  for (int p = 0; p < JREP; ++p){
    float acc = f1b[o];
    for (int c = 0; c < DF; ++c) acc += x2[p*DF+c]*f1w[o*DF+c];
    x1[p*DF+o] = tanhf_(acc);
  }
  __syncthreads();
  for (int p = 0; p < JREP; ++p){
    float acc = f2b[o];
    for (int c = 0; c < DF; ++c) acc += x1[p*DF+c]*f2w[o*DF+c];
    fout[(b*JREP+p)*DF+o] = tanhf_(acc);
  }
}

// ---------------- pack ga_whh (1152x384) f32 -> Wscan f16 [jq][i][g][4] ----------------
__global__ __launch_bounds__(256) void k_wpack(const float* whh, _Float16* wsc){
  int o = blockIdx.x*256 + threadIdx.x;       // < 442368
  int u = o & 3; int g = (o>>2)%3; int rest = (o>>2)/3;
  int i = rest % H1; int jq = rest / H1;
  int j = jq*4 + u;
  wsc[o] = (_Float16)whh[(g*H1+i)*H1 + j];
}

// ---------------- GA tables: GA[k][256][1152] = embed_sig @ ga_wih[:,128k:+128].T ----------------
__global__ __launch_bounds__(256) void k_tables(const float* wih, const float* emb, float* GA){
  __shared__ float Wl[64*129];
  int k = blockIdx.x/18, g0 = (blockIdx.x%18)*64;
  int tid = threadIdx.x;
  for (int idx = tid; idx < 64*128; idx += 256){
    int gg = idx>>7, c = idx&127;
    Wl[gg*129+c] = wih[(size_t)(g0+gg)*INA + k*128 + c];
  }
  __syncthreads();
  int vv = tid>>6, gg = tid&63;
  for (int v = vv; v < 256; v += 4){
    const float* e = emb + (size_t)v*ES;
    float acc = 0.f;
    for (int c = 0; c < 128; ++c) acc += e[c]*Wl[gg*129+c];
    GA[(size_t)(k*256+v)*G3 + g0+gg] = acc;
  }
}

// ---------------- xWrepA[b][j][1152] = f[b][j] @ ga_wih[:,768:896].T + bih + bhh(r,z) ----------------
__global__ __launch_bounds__(256) void k_xwrepA(const float* wih, const float* f,
                                                const float* bih, const float* bhh, float* xwA){
  __shared__ float Wl[64*129];
  int g0 = blockIdx.x*64, tid = threadIdx.x;
  for (int idx = tid; idx < 64*128; idx += 256){
    int gg = idx>>7, c = idx&127;
    Wl[gg*129+c] = wih[(size_t)(g0+gg)*INA + 768 + c];
  }
  __syncthreads();
  int vv = tid>>6, gg = tid&63; int g = g0+gg;
  float badd = bih[g] + (g < 768 ? bhh[g] : 0.f);
  for (int row = vv; row < 64*JREP; row += 4){
    const float* fr = f + (size_t)row*DF;
    float acc = badd;
    for (int c = 0; c < 128; ++c) acc += fr[c]*Wl[gg*129+c];
    xwA[(size_t)row*G3 + g] = acc;
  }
}

// ---------------- xWrepB[b][j][48] ----------------
__global__ __launch_bounds__(256) void k_xwrepB(const float* wih, const float* f,
                                                const float* bih, const float* bhh, float* xwB){
  __shared__ float Wl[48*129];
  int b = blockIdx.x, tid = threadIdx.x;
  for (int idx = tid; idx < 48*128; idx += 256){
    int r = idx>>7, c = idx&127;
    Wl[r*129+c] = wih[r*512 + 384 + c];
  }
  __syncthreads();
  for (int idx = tid; idx < JREP*48; idx += 256){
    int j = idx/48, r = idx%48;
    const float* fr = f + (size_t)(b*JREP+j)*DF;
    float acc = bih[r] + (r < 32 ? bhh[r] : 0.f);
    for (int c = 0; c < 128; ++c) acc += fr[c]*Wl[r*129+c];
    xwB[(size_t)(b*JREP+j)*48 + r] = acc;
  }
}

// ---------------- md2 embed tables: T2[tbl][256 v][256 c] ----------------
__global__ __launch_bounds__(256) void k_t2(const float* w1, const float* w2, const float* emb, float* T2){
  __shared__ float Wl[64*129];
  int tbl = blockIdx.x>>2; int c0 = (blockIdx.x&3)*64; int tid = threadIdx.x;
  const float* w = tbl ? w2 : w1;
  for (int idx = tid; idx < 64*128; idx += 256){
    int cc = idx>>7, e = idx&127;
    Wl[cc*129+e] = w[(c0+cc)*144 + 16 + e];
  }
  __syncthreads();
  int vv = tid>>6, cc = tid&63;
  for (int v = vv; v < 256; v += 4){
    const float* e = emb + (size_t)v*ES;
    float acc = 0.f;
    for (int c = 0; c < 128; ++c) acc += e[c]*Wl[cc*129+c];
    T2[tbl*65536 + v*256 + c0+cc] = acc;
  }
}

// ---------------- GRU-A persistent scan: 1 block per batch ----------------
__global__ __launch_bounds__(768) void k_scanA(const int* in_data, const float* GA, const float* xwA,
        const _Float16* __restrict__ wsc, const float* bhh, _Float16* g1)
{
  __shared__ __align__(16) _Float16 h16[H1];
  __shared__ float pg[H1][5];
  int b = blockIdx.x, tid = threadIdx.x;
  int i = tid % H1, s = tid / H1;
  if (tid < H1) h16[tid] = (_Float16)0.f;
  float hreg = 0.f;
  float bhhn = (s == 0) ? bhh[768 + i] : 0.f;
  const float* tb = GA + (size_t)(s*3)*256*G3;   // tables k = 3s..3s+2
  const _Float16* wp0 = wsc + ((size_t)(s*48)*H1 + i)*12;
  const int* ind_b = in_data + (size_t)b*TT*3;
  __syncthreads();
  for (int t = 0; t < TS; ++t){
    const int* ind = ind_b + (2*t)*3 + s*3;
    int v0 = ind[0], v1 = ind[1], v2 = ind[2];
    const float* r0 = tb + (size_t)v0*G3;
    const float* r1 = tb + (size_t)256*G3 + (size_t)v1*G3;
    const float* r2 = tb + (size_t)512*G3 + (size_t)v2*G3;
    float ar  = r0[i]      + r1[i]      + r2[i];
    float az  = r0[H1+i]   + r1[H1+i]   + r2[H1+i];
    float anx = r0[768+i]  + r1[768+i]  + r2[768+i];
    float ang = 0.f;
    if (s == 1){
      const float* rw = xwA + ((size_t)(b*JREP) + (t/80))*G3;
      ar += rw[i]; az += rw[H1+i]; anx += rw[768+i];
    }
    const _Float16* wp = wp0;
    const h2v* hh = (const h2v*)h16;
    int jq0 = s*48;
    #pragma unroll 4
    for (int q = 0; q < 48; ++q){
      h2v hA = hh[(jq0+q)*2 + 0];
      h2v hB = hh[(jq0+q)*2 + 1];
      const uint2* wu = (const uint2*)wp;
      uint2 wr = wu[0], wz = wu[1], wn = wu[2];
      ar  = fdot2_(hA, bc_h2(wr.x), ar);  ar  = fdot2_(hB, bc_h2(wr.y), ar);
      az  = fdot2_(hA, bc_h2(wz.x), az);  az  = fdot2_(hB, bc_h2(wz.y), az);
      ang = fdot2_(hA, bc_h2(wn.x), ang); ang = fdot2_(hB, bc_h2(wn.y), ang);
      wp += H1*12;
    }
    if (s == 1){ pg[i][0]=ar; pg[i][1]=az; pg[i][2]=anx; pg[i][3]=ang; }
    __syncthreads();
    if (s == 0){
      float R  = ar  + pg[i][0];
      float Z  = az  + pg[i][1];
      float NX = anx + pg[i][2];
      float NG = ang + pg[i][3] + bhhn;
      float r = sigmf_(R), z = sigmf_(Z);
      float n = tanhf_(NX + r*NG);
      float hn = (1.f - z)*n + z*hreg;
      hreg = hn;
      h16[i] = (_Float16)hn;
      g1[((size_t)b*TS + t)*H1 + i] = (_Float16)hn;
    }
    __syncthreads();
  }
}

// ---------------- xW_B = g1 @ gb_wih[:, :384].T + xWrepB ----------------
__global__ __launch_bounds__(256) void k_xwB(const _Float16* g1, const float* wih,
                                             const float* xwrB, float* xwB){
  __shared__ _Float16 gl[16*392];
  int bi = blockIdx.x; int b = bi/55; int t0 = (bi%55)*16; int tid = threadIdx.x;
  for (int idx = tid; idx < 16*H1; idx += 256){
    int tt = idx/H1, c = idx%H1;
    gl[tt*392+c] = g1[((size_t)b*TS + t0+tt)*H1 + c];
  }
  __syncthreads();
  int rr = tid>>4, tt = tid&15;
  int t = t0+tt;
  const float* xr = xwrB + ((size_t)(b*JREP) + t/80)*48;
  for (int rb = 0; rb < 3; ++rb){
    int r = rb*16 + rr;
    const float* wrow = wih + (size_t)r*512;
    float acc = 0.f;
    for (int c = 0; c < H1; ++c) acc += (float)gl[tt*392+c]*wrow[c];
    xwB[((size_t)b*TS + t)*48 + r] = acc + xr[r];
  }
}

// ---------------- GRU-B scan (tiny) ----------------
__global__ __launch_bounds__(64) void k_scanB(const float* xwB, const float* whh,
                                              const float* bhh, float* g2){
  __shared__ float wl[48*17];
  __shared__ float h2s[16];
  __shared__ float pre[32];
  __shared__ float xn[16], gn[16];
  int b = blockIdx.x, tid = threadIdx.x;
  for (int idx = tid; idx < 768; idx += 64) wl[(idx>>4)*17 + (idx&15)] = whh[idx];
  if (tid < 16) h2s[tid] = 0.f;
  float bn = (tid >= 32 && tid < 48) ? bhh[tid] : 0.f;
  __syncthreads();
  for (int t = 0; t < TS; ++t){
    if (tid < 48){
      float xw = xwB[((size_t)b*TS + t)*48 + tid];
      float gh = 0.f;
      for (int e = 0; e < 16; ++e) gh += wl[tid*17+e]*h2s[e];
      if (tid < 32) pre[tid] = xw + gh;
      else { xn[tid-32] = xw; gn[tid-32] = gh + bn; }
    }
    __syncthreads();
    if (tid < 16){
      float r = sigmf_(pre[tid]), z = sigmf_(pre[16+tid]);
      float n = tanhf_(xn[tid] + r*gn[tid]);
      float hn = (1.f - z)*n + z*h2s[tid];
      h2s[tid] = hn;
      g2[((size_t)b*TS + t)*16 + tid] = hn;
    }
    __syncthreads();
  }
}

// ---------------- mdense + output interleave ----------------
__global__ __launch_bounds__(256) void k_out(const float* g2, const int* targets, const float* T2,
    const float* m1w1, const float* m1w2, const float* m1b1, const float* m1b2,
    const float* m1f1, const float* m1f2,
    const float* m2w1, const float* m2w2, const float* m2b1, const float* m2b2,
    const float* m2f1, const float* m2f2, float* out)
{
  __shared__ float wA[256*17], wB[256*17], wC[256*17], wD[256*17];
  __shared__ float g2l[16*16];
  int bi = blockIdx.x; int b = bi/55; int t0 = (bi%55)*16; int c = threadIdx.x;
  for (int d = 0; d < 16; ++d){
    wA[c*17+d] = m1w1[c*16+d];  wB[c*17+d] = m1w2[c*16+d];
    wC[c*17+d] = m2w1[c*144+d]; wD[c*17+d] = m2w2[c*144+d];
  }
  { int tt = c>>4, d = c&15; g2l[c] = g2[((size_t)b*TS + t0+tt)*16 + d]; }
  __syncthreads();
  float b1a = m1b1[c], b2a = m1b2[c], f1a = m1f1[c], f2a = m1f2[c];
  float b1b = m2b1[c], b2b = m2b2[c], f1b = m2f1[c], f2b = m2f2[c];
  for (int tt = 0; tt < 16; ++tt){
    int t = t0+tt;
    float d1 = b1a, d2 = b2a, e1 = b1b, e2 = b2b;
    for (int d = 0; d < 16; ++d){
      float g = g2l[tt*16+d];
      d1 += g*wA[c*17+d]; d2 += g*wB[c*17+d];
      e1 += g*wC[c*17+d]; e2 += g*wD[c*17+d];
    }
    int v = targets[b*TT + 2*t];
    e1 += T2[v*256+c]; e2 += T2[65536 + v*256+c];
    float o1 = f1a*tanhf_(d1) + f2a*tanhf_(d2);
    float o2 = f1b*tanhf_(e1) + f2b*tanhf_(e2);
    size_t base = ((size_t)b*TS + t)*2*256;
    out[base + c]       = o1;
    out[base + 256 + c] = o2;
  }
}

extern "C" void kernel_launch(void* const* d_in, const int* in_sizes, int n_in,
                              void* d_out, int out_size, void* d_ws, size_t ws_size,
                              hipStream_t stream) {
  const int*   in_data = (const int*)  d_in[0];
  const float* feat    = (const float*)d_in[1];
  const int*   periods = (const int*)  d_in[2];
  const int*   targets = (const int*)  d_in[3];
  const float* embp    = (const float*)d_in[4];
  const float* embs    = (const float*)d_in[5];
  const float* c1w = (const float*)d_in[6];  const float* c1b = (const float*)d_in[7];
  const float* c2w = (const float*)d_in[8];  const float* c2b = (const float*)d_in[9];
  const float* f1w = (const float*)d_in[10]; const float* f1b = (const float*)d_in[11];
  const float* f2w = (const float*)d_in[12]; const float* f2b = (const float*)d_in[13];
  const float* ga_wih = (const float*)d_in[14]; const float* ga_whh = (const float*)d_in[15];
  const float* ga_bih = (const float*)d_in[16]; const float* ga_bhh = (const float*)d_in[17];
  const float* gb_wih = (const float*)d_in[18]; const float* gb_whh = (const float*)d_in[19];
  const float* gb_bih = (const float*)d_in[20]; const float* gb_bhh = (const float*)d_in[21];
  const float* m1w1 = (const float*)d_in[22]; const float* m1w2 = (const float*)d_in[23];
  const float* m1b1 = (const float*)d_in[24]; const float* m1b2 = (const float*)d_in[25];
  const float* m1f1 = (const float*)d_in[26]; const float* m1f2 = (const float*)d_in[27];
  const float* m2w1 = (const float*)d_in[28]; const float* m2w2 = (const float*)d_in[29];
  const float* m2b1 = (const float*)d_in[30]; const float* m2b2 = (const float*)d_in[31];
  const float* m2f1 = (const float*)d_in[32]; const float* m2f2 = (const float*)d_in[33];
  float* out = (float*)d_out;

  // workspace layout (floats)
  float* GA     = (float*)d_ws;                  // 6*256*1152     = 1,769,472
  float* xWrepA = GA     + 1769472;              // 704*1152       =   811,008
  float* xWrepB = xWrepA + 811008;               // 704*48         =    33,792
  float* fbuf   = xWrepB + 33792;                // 704*128        =    90,112
  float* xWB    = fbuf   + 90112;                // 56320*48       = 2,703,360
  float* g2buf  = xWB    + 2703360;              // 56320*16       =   901,120
  float* T2     = g2buf  + 901120;               // 2*256*256      =   131,072
  _Float16* Wscan = (_Float16*)(T2 + 131072);    // 442,368 halves
  _Float16* g1  = (_Float16*)d_out;              // scratch inside output buffer (43.3MB < 115MB)

  hipLaunchKernelGGL(k_frame, dim3(64), dim3(128), 0, stream,
                     feat, periods, embp, c1w, c1b, c2w, c2b, f1w, f1b, f2w, f2b, fbuf);
  hipLaunchKernelGGL(k_wpack, dim3(1728), dim3(256), 0, stream, ga_whh, Wscan);
  hipLaunchKernelGGL(k_tables, dim3(108), dim3(256), 0, stream, ga_wih, embs, GA);
  hipLaunchKernelGGL(k_t2, dim3(8), dim3(256), 0, stream, m2w1, m2w2, embs, T2);
  hipLaunchKernelGGL(k_xwrepA, dim3(18), dim3(256), 0, stream, ga_wih, fbuf, ga_bih, ga_bhh, xWrepA);
  hipLaunchKernelGGL(k_xwrepB, dim3(64), dim3(256), 0, stream, gb_wih, fbuf, gb_bih, gb_bhh, xWrepB);
  hipLaunchKernelGGL(k_scanA, dim3(64), dim3(768), 0, stream, in_data, GA, xWrepA, Wscan, ga_bhh, g1);
  hipLaunchKernelGGL(k_xwB, dim3(64*55), dim3(256), 0, stream, g1, gb_wih, xWrepB, xWB);
  hipLaunchKernelGGL(k_scanB, dim3(64), dim3(64), 0, stream, xWB, gb_whh, gb_bhh, g2buf);
  hipLaunchKernelGGL(k_out, dim3(64*55), dim3(256), 0, stream,
                     g2buf, targets, T2, m1w1, m1w2, m1b1, m1b2, m1f1, m1f2,
                     m2w1, m2w2, m2b1, m2b2, m2f1, m2f2, out);
}

// Round 2
// 5562.927 us; speedup vs baseline: 1.7804x; 1.7804x over previous
//
#include <hip/hip_runtime.h>
#include <hip/hip_bf16.h>
#include <hip/hip_fp16.h>

#define NF    15
#define NBF   20
#define TT    1760
#define TS    880
#define EP    64
#define ES    128
#define DF    128
#define H1    384
#define G3    1152
#define INA   896
#define JREP  11

typedef _Float16 h2v __attribute__((ext_vector_type(2)));

__device__ __forceinline__ float sigmf_(float x){ return 1.0f/(1.0f + __expf(-x)); }
__device__ __forceinline__ float tanhf_(float x){ return 2.0f/(1.0f + __expf(-2.0f*x)) - 1.0f; }
__device__ __forceinline__ h2v bc_h2(unsigned u){ return __builtin_bit_cast(h2v, u); }
__device__ __forceinline__ float fdot2_(h2v a, h2v b, float c){
#if __has_builtin(__builtin_amdgcn_fdot2)
  return __builtin_amdgcn_fdot2(a, b, c, false);
#else
  return c + (float)a[0]*(float)b[0] + (float)a[1]*(float)b[1];
#endif
}

// ---------------- frame-rate network: f[64][11][128] ----------------
__global__ __launch_bounds__(128) void k_frame(const float* feat, const int* periods, const float* embp,
   const float* c1w, const float* c1b, const float* c2w, const float* c2b,
   const float* f1w, const float* f1b, const float* f2w, const float* f2b, float* fout)
{
  __shared__ float cat[NF*84];
  __shared__ float x1[13*DF];
  __shared__ float x2[JREP*DF];
  int b = blockIdx.x, tid = threadIdx.x;
  for (int idx = tid; idx < NF*84; idx += 128){
    int j = idx/84, c = idx%84;
    cat[idx] = (c < NBF) ? feat[(b*NF+j)*NBF + c]
                         : embp[periods[b*NF+j]*EP + (c-NBF)];
  }
  __syncthreads();
  int o = tid;
  for (int p = 0; p < 13; ++p){
    float acc = c1b[o];
    for (int kk = 0; kk < 3; ++kk)
      for (int c = 0; c < 84; ++c)
        acc += cat[(p+kk)*84 + c] * c1w[(o*84+c)*3+kk];
    x1[p*DF+o] = tanhf_(acc);
  }
  __syncthreads();
  for (int p = 0; p < JREP; ++p){
    float acc = c2b[o];
    for (int kk = 0; kk < 3; ++kk)
      for (int c = 0; c < DF; ++c)
        acc += x1[(p+kk)*DF+c] * c2w[(o*DF+c)*3+kk];
    x2[p*DF+o] = tanhf_(acc);
  }
  __syncthreads();
  for (int p = 0; p < JREP; ++p){
    float acc = f1b[o];
    for (int c = 0; c < DF; ++c) acc += x2[p*DF+c]*f1w[o*DF+c];
    x1[p*DF+o] = tanhf_(acc);
  }
  __syncthreads();
  for (int p = 0; p < JREP; ++p){
    float acc = f2b[o];
    for (int c = 0; c < DF; ++c) acc += x1[p*DF+c]*f2w[o*DF+c];
    fout[(b*JREP+p)*DF+o] = tanhf_(acc);
  }
}

// ---------------- pack ga_whh (1152x384) f32 -> per-thread-contiguous f16 chunks ----------------
// layout: wpk[(o8*1536 + tpos)*8 + u8], tpos = hf*768 + tid, o8 in [0,36), u8 in [0,8)
// thread (hf,tid): il=tid%192, s=tid/192, Q=(s&1)+2*((s>>1)^hf)
// m = o8*8+u8 in [0,288): q=m/12, g=(m%12)/4, u=m%4 ; j=Q*96+q*4+u ; i=hf*192+il
__global__ __launch_bounds__(256) void k_wpack2(const float* whh, _Float16* wpk){
  int o = blockIdx.x*256 + threadIdx.x;        // < 442368
  int u8 = o & 7; int idx = o >> 3;
  int tpos = idx % 1536; int o8 = idx / 1536;
  int tid = tpos % 768; int hf = tpos / 768;
  int il = tid % 192; int s = tid / 192;
  int Q = (s & 1) + 2*((s >> 1) ^ hf);
  int m = o8*8 + u8;
  int q = m / 12, rem = m % 12;
  int g = rem / 4, u = rem % 4;
  int j = Q*96 + q*4 + u;
  int i = hf*192 + il;
  wpk[o] = (_Float16)whh[(g*H1 + i)*H1 + j];
}

// ---------------- GA tables: GA[k][256][1152] ----------------
__global__ __launch_bounds__(256) void k_tables(const float* wih, const float* emb, float* GA){
  __shared__ float Wl[64*129];
  int k = blockIdx.x/18, g0 = (blockIdx.x%18)*64;
  int tid = threadIdx.x;
  for (int idx = tid; idx < 64*128; idx += 256){
    int gg = idx>>7, c = idx&127;
    Wl[gg*129+c] = wih[(size_t)(g0+gg)*INA + k*128 + c];
  }
  __syncthreads();
  int vv = tid>>6, gg = tid&63;
  for (int v = vv; v < 256; v += 4){
    const float* e = emb + (size_t)v*ES;
    float acc = 0.f;
    for (int c = 0; c < 128; ++c) acc += e[c]*Wl[gg*129+c];
    GA[(size_t)(k*256+v)*G3 + g0+gg] = acc;
  }
}

// ---------------- xWrepA[b][j][1152] ----------------
__global__ __launch_bounds__(256) void k_xwrepA(const float* wih, const float* f,
                                                const float* bih, const float* bhh, float* xwA){
  __shared__ float Wl[64*129];
  int g0 = blockIdx.x*64, tid = threadIdx.x;
  for (int idx = tid; idx < 64*128; idx += 256){
    int gg = idx>>7, c = idx&127;
    Wl[gg*129+c] = wih[(size_t)(g0+gg)*INA + 768 + c];
  }
  __syncthreads();
  int vv = tid>>6, gg = tid&63; int g = g0+gg;
  float badd = bih[g] + (g < 768 ? bhh[g] : 0.f);
  for (int row = vv; row < 64*JREP; row += 4){
    const float* fr = f + (size_t)row*DF;
    float acc = badd;
    for (int c = 0; c < 128; ++c) acc += fr[c]*Wl[gg*129+c];
    xwA[(size_t)row*G3 + g] = acc;
  }
}

// ---------------- xWrepB[b][j][48] ----------------
__global__ __launch_bounds__(256) void k_xwrepB(const float* wih, const float* f,
                                                const float* bih, const float* bhh, float* xwB){
  __shared__ float Wl[48*129];
  int b = blockIdx.x, tid = threadIdx.x;
  for (int idx = tid; idx < 48*128; idx += 256){
    int r = idx>>7, c = idx&127;
    Wl[r*129+c] = wih[r*512 + 384 + c];
  }
  __syncthreads();
  for (int idx = tid; idx < JREP*48; idx += 256){
    int j = idx/48, r = idx%48;
    const float* fr = f + (size_t)(b*JREP+j)*DF;
    float acc = bih[r] + (r < 32 ? bhh[r] : 0.f);
    for (int c = 0; c < 128; ++c) acc += fr[c]*Wl[r*129+c];
    xwB[(size_t)(b*JREP+j)*48 + r] = acc;
  }
}

// ---------------- md2 embed tables: T2[tbl][256][256] ----------------
__global__ __launch_bounds__(256) void k_t2(const float* w1, const float* w2, const float* emb, float* T2){
  __shared__ float Wl[64*129];
  int tbl = blockIdx.x>>2; int c0 = (blockIdx.x&3)*64; int tid = threadIdx.x;
  const float* w = tbl ? w2 : w1;
  for (int idx = tid; idx < 64*128; idx += 256){
    int cc = idx>>7, e = idx&127;
    Wl[cc*129+e] = w[(c0+cc)*144 + 16 + e];
  }
  __syncthreads();
  int vv = tid>>6, cc = tid&63;
  for (int v = vv; v < 256; v += 4){
    const float* e = emb + (size_t)v*ES;
    float acc = 0.f;
    for (int c = 0; c < 128; ++c) acc += e[c]*Wl[cc*129+c];
    T2[tbl*65536 + v*256 + c0+cc] = acc;
  }
}

// ---------------- GRU-A weight-stationary scan: 2 blocks per batch ----------------
// block P: b = P&63, hf = P>>6. Owns output rows [hf*192, hf*192+192).
// thread: il=tid%192, s=tid/192; j-quarter Q=(s&1)+2*((s>>1)^hf); 144 h2v weights in VGPRs.
// s in {0,1}: own-half j (no wait). s in {2,3}: partner-half j (poll+copy first).
__global__ __launch_bounds__(768) void k_scanA2(const int* in_data, const float* GA, const float* xwA,
        const uint4* __restrict__ wpk, const float* bhh, _Float16* g1,
        _Float16* hx, int* flags)
{
  __shared__ __align__(8) _Float16 h16[H1];
  __shared__ float pg[192][10];
  const int P = blockIdx.x;
  const int b = P & 63, hf = P >> 6;
  const int tid = threadIdx.x;
  const int il = tid % 192;
  const int s  = tid / 192;
  const int ig = hf*192 + il;
  const int Q  = (s & 1) + 2*((s >> 1) ^ hf);

  h2v w[144];
  {
    const uint4* src = wpk + (size_t)(hf*768 + tid);
    #pragma unroll
    for (int o8 = 0; o8 < 36; ++o8){
      uint4 d = src[(size_t)o8*1536];
      w[o8*4+0]=bc_h2(d.x); w[o8*4+1]=bc_h2(d.y);
      w[o8*4+2]=bc_h2(d.z); w[o8*4+3]=bc_h2(d.w);
    }
  }
  if (tid < 192) ((unsigned*)h16)[tid] = 0u;
  float hreg = 0.f;
  float bhhn = (s == 0) ? bhh[768 + ig] : 0.f;
  const int* ind_b = in_data + (size_t)b*TT*3;
  const _Float16* hxp = hx + (size_t)((b*2 + (1-hf))*2)*192;
  _Float16*       hxo = hx + (size_t)((b*2 + hf)*2)*192;
  int* flgp = flags + (P ^ 64);
  int* flgo = flags + P;
  const int jq0 = Q*24;
  const h2v* hh = (const h2v*)h16;
  __syncthreads();

  for (int t = 0; t < TS; ++t){
    float ar=0.f, az=0.f, ang=0.f;
    float xr=0.f, xz=0.f, xnx=0.f;
    if (s < 2){
      if (s == 0){
        const int* ind = ind_b + (2*t)*3;
        #pragma unroll
        for (int k2 = 0; k2 < 6; ++k2){
          int v = ind[k2];
          const float* r = GA + ((size_t)k2*256 + v)*G3;
          xr += r[ig]; xz += r[H1+ig]; xnx += r[768+ig];
        }
        const float* rw = xwA + ((size_t)(b*JREP) + (t/80))*G3;
        xr += rw[ig]; xz += rw[H1+ig]; xnx += rw[768+ig];
      }
      #pragma unroll
      for (int q = 0; q < 24; ++q){
        h2v hA = hh[(jq0+q)*2+0], hB = hh[(jq0+q)*2+1];
        ar = fdot2_(hA,w[q*6+0],ar); ar = fdot2_(hB,w[q*6+1],ar);
        az = fdot2_(hA,w[q*6+2],az); az = fdot2_(hB,w[q*6+3],az);
        ang= fdot2_(hA,w[q*6+4],ang);ang= fdot2_(hB,w[q*6+5],ang);
      }
      if (s == 1){ pg[il][0]=ar; pg[il][1]=az; pg[il][2]=ang; }
    } else {
      if (t > 0){
        while (__hip_atomic_load(flgp, __ATOMIC_RELAXED, __HIP_MEMORY_SCOPE_AGENT) < t) { }
        if (tid < 480){
          int k = tid - 384;
          const unsigned* srcu = (const unsigned*)(hxp + (size_t)((t-1)&1)*192);
          unsigned u = __hip_atomic_load(srcu + k, __ATOMIC_RELAXED, __HIP_MEMORY_SCOPE_AGENT);
          ((unsigned*)h16)[(1-hf)*96 + k] = u;
        }
      }
    }
    __syncthreads();                          // B: partner half of h ready in LDS
    if (s >= 2){
      #pragma unroll
      for (int q = 0; q < 24; ++q){
        h2v hA = hh[(jq0+q)*2+0], hB = hh[(jq0+q)*2+1];
        ar = fdot2_(hA,w[q*6+0],ar); ar = fdot2_(hB,w[q*6+1],ar);
        az = fdot2_(hA,w[q*6+2],az); az = fdot2_(hB,w[q*6+3],az);
        ang= fdot2_(hA,w[q*6+4],ang);ang= fdot2_(hB,w[q*6+5],ang);
      }
      pg[il][(s-1)*3+0]=ar; pg[il][(s-1)*3+1]=az; pg[il][(s-1)*3+2]=ang;
    }
    __syncthreads();                          // C: all partials in
    if (s == 0){
      float R  = ar  + pg[il][0] + pg[il][3] + pg[il][6] + xr;
      float Z  = az  + pg[il][1] + pg[il][4] + pg[il][7] + xz;
      float NG = ang + pg[il][2] + pg[il][5] + pg[il][8] + bhhn;
      float r = sigmf_(R), z = sigmf_(Z);
      float n = tanhf_(xnx + r*NG);
      float hn = (1.f - z)*n + z*hreg;
      hreg = hn;
      _Float16 hv = (_Float16)hn;
      h16[ig] = hv;
      g1[((size_t)b*TS + t)*H1 + ig] = hv;
      __hip_atomic_store((unsigned short*)(hxo + (size_t)(t&1)*192) + il,
                         __builtin_bit_cast(unsigned short, hv),
                         __ATOMIC_RELAXED, __HIP_MEMORY_SCOPE_AGENT);
    }
    __syncthreads();                          // A: drains h' stores (vmcnt 0 before barrier)
    if (tid == 0)
      __hip_atomic_store(flgo, t+1, __ATOMIC_RELAXED, __HIP_MEMORY_SCOPE_AGENT);
  }
}

// ---------------- xW_B = g1 @ gb_wih[:, :384].T + xWrepB ----------------
__global__ __launch_bounds__(256) void k_xwB(const _Float16* g1, const float* wih,
                                             const float* xwrB, float* xwB){
  __shared__ _Float16 gl[16*392];
  int bi = blockIdx.x; int b = bi/55; int t0 = (bi%55)*16; int tid = threadIdx.x;
  for (int idx = tid; idx < 16*H1; idx += 256){
    int tt = idx/H1, c = idx%H1;
    gl[tt*392+c] = g1[((size_t)b*TS + t0+tt)*H1 + c];
  }
  __syncthreads();
  int rr = tid>>4, tt = tid&15;
  int t = t0+tt;
  const float* xr = xwrB + ((size_t)(b*JREP) + t/80)*48;
  for (int rb = 0; rb < 3; ++rb){
    int r = rb*16 + rr;
    const float* wrow = wih + (size_t)r*512;
    float acc = 0.f;
    for (int c = 0; c < H1; ++c) acc += (float)gl[tt*392+c]*wrow[c];
    xwB[((size_t)b*TS + t)*48 + r] = acc + xr[r];
  }
}

// ---------------- GRU-B scan (tiny) ----------------
__global__ __launch_bounds__(64) void k_scanB(const float* xwB, const float* whh,
                                              const float* bhh, float* g2){
  __shared__ float wl[48*17];
  __shared__ float h2s[16];
  __shared__ float pre[32];
  __shared__ float xn[16], gn[16];
  int b = blockIdx.x, tid = threadIdx.x;
  for (int idx = tid; idx < 768; idx += 64) wl[(idx>>4)*17 + (idx&15)] = whh[idx];
  if (tid < 16) h2s[tid] = 0.f;
  float bn = (tid >= 32 && tid < 48) ? bhh[tid] : 0.f;
  __syncthreads();
  for (int t = 0; t < TS; ++t){
    if (tid < 48){
      float xw = xwB[((size_t)b*TS + t)*48 + tid];
      float gh = 0.f;
      for (int e = 0; e < 16; ++e) gh += wl[tid*17+e]*h2s[e];
      if (tid < 32) pre[tid] = xw + gh;
      else { xn[tid-32] = xw; gn[tid-32] = gh + bn; }
    }
    __syncthreads();
    if (tid < 16){
      float r = sigmf_(pre[tid]), z = sigmf_(pre[16+tid]);
      float n = tanhf_(xn[tid] + r*gn[tid]);
      float hn = (1.f - z)*n + z*h2s[tid];
      h2s[tid] = hn;
      g2[((size_t)b*TS + t)*16 + tid] = hn;
    }
    __syncthreads();
  }
}

// ---------------- mdense + output interleave ----------------
__global__ __launch_bounds__(256) void k_out(const float* g2, const int* targets, const float* T2,
    const float* m1w1, const float* m1w2, const float* m1b1, const float* m1b2,
    const float* m1f1, const float* m1f2,
    const float* m2w1, const float* m2w2, const float* m2b1, const float* m2b2,
    const float* m2f1, const float* m2f2, float* out)
{
  __shared__ float wA[256*17], wB[256*17], wC[256*17], wD[256*17];
  __shared__ float g2l[16*16];
  int bi = blockIdx.x; int b = bi/55; int t0 = (bi%55)*16; int c = threadIdx.x;
  for (int d = 0; d < 16; ++d){
    wA[c*17+d] = m1w1[c*16+d];  wB[c*17+d] = m1w2[c*16+d];
    wC[c*17+d] = m2w1[c*144+d]; wD[c*17+d] = m2w2[c*144+d];
  }
  { int tt = c>>4, d = c&15; g2l[c] = g2[((size_t)b*TS + t0+tt)*16 + d]; }
  __syncthreads();
  float b1a = m1b1[c], b2a = m1b2[c], f1a = m1f1[c], f2a = m1f2[c];
  float b1b = m2b1[c], b2b = m2b2[c], f1b = m2f1[c], f2b = m2f2[c];
  for (int tt = 0; tt < 16; ++tt){
    int t = t0+tt;
    float d1 = b1a, d2 = b2a, e1 = b1b, e2 = b2b;
    for (int d = 0; d < 16; ++d){
      float g = g2l[tt*16+d];
      d1 += g*wA[c*17+d]; d2 += g*wB[c*17+d];
      e1 += g*wC[c*17+d]; e2 += g*wD[c*17+d];
    }
    int v = targets[b*TT + 2*t];
    e1 += T2[v*256+c]; e2 += T2[65536 + v*256+c];
    float o1 = f1a*tanhf_(d1) + f2a*tanhf_(d2);
    float o2 = f1b*tanhf_(e1) + f2b*tanhf_(e2);
    size_t base = ((size_t)b*TS + t)*2*256;
    out[base + c]       = o1;
    out[base + 256 + c] = o2;
  }
}

extern "C" void kernel_launch(void* const* d_in, const int* in_sizes, int n_in,
                              void* d_out, int out_size, void* d_ws, size_t ws_size,
                              hipStream_t stream) {
  const int*   in_data = (const int*)  d_in[0];
  const float* feat    = (const float*)d_in[1];
  const int*   periods = (const int*)  d_in[2];
  const int*   targets = (const int*)  d_in[3];
  const float* embp    = (const float*)d_in[4];
  const float* embs    = (const float*)d_in[5];
  const float* c1w = (const float*)d_in[6];  const float* c1b = (const float*)d_in[7];
  const float* c2w = (const float*)d_in[8];  const float* c2b = (const float*)d_in[9];
  const float* f1w = (const float*)d_in[10]; const float* f1b = (const float*)d_in[11];
  const float* f2w = (const float*)d_in[12]; const float* f2b = (const float*)d_in[13];
  const float* ga_wih = (const float*)d_in[14]; const float* ga_whh = (const float*)d_in[15];
  const float* ga_bih = (const float*)d_in[16]; const float* ga_bhh = (const float*)d_in[17];
  const float* gb_wih = (const float*)d_in[18]; const float* gb_whh = (const float*)d_in[19];
  const float* gb_bih = (const float*)d_in[20]; const float* gb_bhh = (const float*)d_in[21];
  const float* m1w1 = (const float*)d_in[22]; const float* m1w2 = (const float*)d_in[23];
  const float* m1b1 = (const float*)d_in[24]; const float* m1b2 = (const float*)d_in[25];
  const float* m1f1 = (const float*)d_in[26]; const float* m1f2 = (const float*)d_in[27];
  const float* m2w1 = (const float*)d_in[28]; const float* m2w2 = (const float*)d_in[29];
  const float* m2b1 = (const float*)d_in[30]; const float* m2b2 = (const float*)d_in[31];
  const float* m2f1 = (const float*)d_in[32]; const float* m2f2 = (const float*)d_in[33];
  float* out = (float*)d_out;

  // workspace layout (floats)
  float* GA     = (float*)d_ws;                  // 6*256*1152     = 1,769,472
  float* xWrepA = GA     + 1769472;              // 704*1152       =   811,008
  float* xWrepB = xWrepA + 811008;               // 704*48         =    33,792
  float* fbuf   = xWrepB + 33792;                // 704*128        =    90,112
  float* xWB    = fbuf   + 90112;                // 56320*48       = 2,703,360
  float* g2buf  = xWB    + 2703360;              // 56320*16       =   901,120
  float* T2     = g2buf  + 901120;               // 2*256*256      =   131,072
  _Float16* Wpk = (_Float16*)(T2 + 131072);      // 442,368 halves
  _Float16* hx  = Wpk + 442368;                  // 64*2*2*192     =    98,304 halves
  int*  flags   = (int*)(hx + 98304);            // 128 ints
  _Float16* g1  = (_Float16*)d_out;              // scratch inside output buffer (43.3MB < 115MB)

  hipMemsetAsync(flags, 0, 128*sizeof(int), stream);
  hipLaunchKernelGGL(k_frame, dim3(64), dim3(128), 0, stream,
                     feat, periods, embp, c1w, c1b, c2w, c2b, f1w, f1b, f2w, f2b, fbuf);
  hipLaunchKernelGGL(k_wpack2, dim3(1728), dim3(256), 0, stream, ga_whh, Wpk);
  hipLaunchKernelGGL(k_tables, dim3(108), dim3(256), 0, stream, ga_wih, embs, GA);
  hipLaunchKernelGGL(k_t2, dim3(8), dim3(256), 0, stream, m2w1, m2w2, embs, T2);
  hipLaunchKernelGGL(k_xwrepA, dim3(18), dim3(256), 0, stream, ga_wih, fbuf, ga_bih, ga_bhh, xWrepA);
  hipLaunchKernelGGL(k_xwrepB, dim3(64), dim3(256), 0, stream, gb_wih, fbuf, gb_bih, gb_bhh, xWrepB);
  hipLaunchKernelGGL(k_scanA2, dim3(128), dim3(768), 0, stream,
                     in_data, GA, xWrepA, (const uint4*)Wpk, ga_bhh, g1, hx, flags);
  hipLaunchKernelGGL(k_xwB, dim3(64*55), dim3(256), 0, stream, g1, gb_wih, xWrepB, xWB);
  hipLaunchKernelGGL(k_scanB, dim3(64), dim3(64), 0, stream, xWB, gb_whh, gb_bhh, g2buf);
  hipLaunchKernelGGL(k_out, dim3(64*55), dim3(256), 0, stream,
                     g2buf, targets, T2, m1w1, m1w2, m1b1, m1b2, m1f1, m1f2,
                     m2w1, m2w2, m2b1, m2b2, m2f1, m2f2, out);
}

// Round 3
// 5009.351 us; speedup vs baseline: 1.9772x; 1.1105x over previous
//
#include <hip/hip_runtime.h>
#include <hip/hip_bf16.h>
#include <hip/hip_fp16.h>

#define NF    15
#define NBF   20
#define TT    1760
#define TS    880
#define EP    64
#define ES    128
#define DF    128
#define H1    384
#define G3    1152
#define INA   896
#define JREP  11

typedef _Float16 h2v __attribute__((ext_vector_type(2)));

__device__ __forceinline__ float sigmf_(float x){ return 1.0f/(1.0f + __expf(-x)); }
__device__ __forceinline__ float tanhf_(float x){ return 2.0f/(1.0f + __expf(-2.0f*x)) - 1.0f; }
__device__ __forceinline__ h2v bc_h2(unsigned u){ return __builtin_bit_cast(h2v, u); }
__device__ __forceinline__ float fdot2_(h2v a, h2v b, float c){
#if __has_builtin(__builtin_amdgcn_fdot2)
  return __builtin_amdgcn_fdot2(a, b, c, false);
#else
  return c + (float)a[0]*(float)b[0] + (float)a[1]*(float)b[1];
#endif
}

// ---------------- frame-rate network: f[64][11][128] ----------------
__global__ __launch_bounds__(128) void k_frame(const float* feat, const int* periods, const float* embp,
   const float* c1w, const float* c1b, const float* c2w, const float* c2b,
   const float* f1w, const float* f1b, const float* f2w, const float* f2b, float* fout)
{
  __shared__ float cat[NF*84];
  __shared__ float x1[13*DF];
  __shared__ float x2[JREP*DF];
  int b = blockIdx.x, tid = threadIdx.x;
  for (int idx = tid; idx < NF*84; idx += 128){
    int j = idx/84, c = idx%84;
    cat[idx] = (c < NBF) ? feat[(b*NF+j)*NBF + c]
                         : embp[periods[b*NF+j]*EP + (c-NBF)];
  }
  __syncthreads();
  int o = tid;
  for (int p = 0; p < 13; ++p){
    float acc = c1b[o];
    for (int kk = 0; kk < 3; ++kk)
      for (int c = 0; c < 84; ++c)
        acc += cat[(p+kk)*84 + c] * c1w[(o*84+c)*3+kk];
    x1[p*DF+o] = tanhf_(acc);
  }
  __syncthreads();
  for (int p = 0; p < JREP; ++p){
    float acc = c2b[o];
    for (int kk = 0; kk < 3; ++kk)
      for (int c = 0; c < DF; ++c)
        acc += x1[(p+kk)*DF+c] * c2w[(o*DF+c)*3+kk];
    x2[p*DF+o] = tanhf_(acc);
  }
  __syncthreads();
  for (int p = 0; p < JREP; ++p){
    float acc = f1b[o];
    for (int c = 0; c < DF; ++c) acc += x2[p*DF+c]*f1w[o*DF+c];
    x1[p*DF+o] = tanhf_(acc);
  }
  __syncthreads();
  for (int p = 0; p < JREP; ++p){
    float acc = f2b[o];
    for (int c = 0; c < DF; ++c) acc += x1[p*DF+c]*f2w[o*DF+c];
    fout[(b*JREP+p)*DF+o] = tanhf_(acc);
  }
}

// ---------------- pack ga_whh f32 -> per-(hf,thread) uint4-contiguous f16 ----------------
// consumed as: block hf, thread tid (r=tid%96, s=tid/96):
//   d_i = wpk4[(hf*18 + i)*768 + tid], i in [0,18)
//   dword gd = i*4+c : q=gd/6, k6=gd%6, g=k6>>1, hsel=k6&1
//   jbase = ((hf ^ (s>>1))*2 + (s&1))*48 ; half u: j = jbase + 4q + 2*hsel + u ; row i = hf*96 + r
__global__ __launch_bounds__(256) void k_wpack3(const float* whh, _Float16* wpk){
  int o = blockIdx.x*256 + threadIdx.x;        // < 442368
  int u  = o & 1;
  int c  = (o >> 1) & 3;
  int idx = o >> 3;                            // uint4 index
  int tid = idx % 768;
  int i18 = (idx / 768) % 18;
  int hf  = idx / (768*18);
  int r = tid % 96, s = tid / 96;
  int gd = i18*4 + c;
  int q = gd / 6, k6 = gd % 6;
  int g = k6 >> 1, hsel = k6 & 1;
  int jbase = ((hf ^ (s >> 1))*2 + (s & 1))*48;
  int j = jbase + 4*q + 2*hsel + u;
  int i = hf*96 + r;
  wpk[o] = (_Float16)whh[(g*H1 + i)*H1 + j];
}

// ---------------- GA tables: GA[k][256][1152] ----------------
__global__ __launch_bounds__(256) void k_tables(const float* wih, const float* emb, float* GA){
  __shared__ float Wl[64*129];
  int k = blockIdx.x/18, g0 = (blockIdx.x%18)*64;
  int tid = threadIdx.x;
  for (int idx = tid; idx < 64*128; idx += 256){
    int gg = idx>>7, c = idx&127;
    Wl[gg*129+c] = wih[(size_t)(g0+gg)*INA + k*128 + c];
  }
  __syncthreads();
  int vv = tid>>6, gg = tid&63;
  for (int v = vv; v < 256; v += 4){
    const float* e = emb + (size_t)v*ES;
    float acc = 0.f;
    for (int c = 0; c < 128; ++c) acc += e[c]*Wl[gg*129+c];
    GA[(size_t)(k*256+v)*G3 + g0+gg] = acc;
  }
}

// ---------------- xWrepA[b][j][1152] ----------------
__global__ __launch_bounds__(256) void k_xwrepA(const float* wih, const float* f,
                                                const float* bih, const float* bhh, float* xwA){
  __shared__ float Wl[64*129];
  int g0 = blockIdx.x*64, tid = threadIdx.x;
  for (int idx = tid; idx < 64*128; idx += 256){
    int gg = idx>>7, c = idx&127;
    Wl[gg*129+c] = wih[(size_t)(g0+gg)*INA + 768 + c];
  }
  __syncthreads();
  int vv = tid>>6, gg = tid&63; int g = g0+gg;
  float badd = bih[g] + (g < 768 ? bhh[g] : 0.f);
  for (int row = vv; row < 64*JREP; row += 4){
    const float* fr = f + (size_t)row*DF;
    float acc = badd;
    for (int c = 0; c < 128; ++c) acc += fr[c]*Wl[gg*129+c];
    xwA[(size_t)row*G3 + g] = acc;
  }
}

// ---------------- xWrepB[b][j][48] ----------------
__global__ __launch_bounds__(256) void k_xwrepB(const float* wih, const float* f,
                                                const float* bih, const float* bhh, float* xwB){
  __shared__ float Wl[48*129];
  int b = blockIdx.x, tid = threadIdx.x;
  for (int idx = tid; idx < 48*128; idx += 256){
    int r = idx>>7, c = idx&127;
    Wl[r*129+c] = wih[r*512 + 384 + c];
  }
  __syncthreads();
  for (int idx = tid; idx < JREP*48; idx += 256){
    int j = idx/48, r = idx%48;
    const float* fr = f + (size_t)(b*JREP+j)*DF;
    float acc = bih[r] + (r < 32 ? bhh[r] : 0.f);
    for (int c = 0; c < 128; ++c) acc += fr[c]*Wl[r*129+c];
    xwB[(size_t)(b*JREP+j)*48 + r] = acc;
  }
}

// ---------------- md2 embed tables: T2[tbl][256][256] ----------------
__global__ __launch_bounds__(256) void k_t2(const float* w1, const float* w2, const float* emb, float* T2){
  __shared__ float Wl[64*129];
  int tbl = blockIdx.x>>2; int c0 = (blockIdx.x&3)*64; int tid = threadIdx.x;
  const float* w = tbl ? w2 : w1;
  for (int idx = tid; idx < 64*128; idx += 256){
    int cc = idx>>7, e = idx&127;
    Wl[cc*129+e] = w[(c0+cc)*144 + 16 + e];
  }
  __syncthreads();
  int vv = tid>>6, cc = tid&63;
  for (int v = vv; v < 256; v += 4){
    const float* e = emb + (size_t)v*ES;
    float acc = 0.f;
    for (int c = 0; c < 128; ++c) acc += e[c]*Wl[cc*129+c];
    T2[tbl*65536 + v*256 + c0+cc] = acc;
  }
}

// ---------------- GRU-A weight-stationary scan: 4 blocks per batch ----------------
#define LD18(n) uint4 d##n = wsrc[(size_t)(n)*768];
#define Q2(A,B,C, q2) { \
  h2v hA = hh[jb2 + (q2)*2],     hB = hh[jb2 + (q2)*2 + 1]; \
  ar = fdot2_(hA, bc_h2(A.x), ar); ar = fdot2_(hB, bc_h2(A.y), ar); \
  az = fdot2_(hA, bc_h2(A.z), az); az = fdot2_(hB, bc_h2(A.w), az); \
  an = fdot2_(hA, bc_h2(B.x), an); an = fdot2_(hB, bc_h2(B.y), an); \
  h2v hC = hh[jb2 + (q2)*2 + 2], hD = hh[jb2 + (q2)*2 + 3]; \
  ar = fdot2_(hC, bc_h2(B.z), ar); ar = fdot2_(hD, bc_h2(B.w), ar); \
  az = fdot2_(hC, bc_h2(C.x), az); az = fdot2_(hD, bc_h2(C.y), az); \
  an = fdot2_(hC, bc_h2(C.z), an); an = fdot2_(hD, bc_h2(C.w), an); }
#define DOTS12 \
  Q2(d0,d1,d2,0) Q2(d3,d4,d5,2) Q2(d6,d7,d8,4) \
  Q2(d9,d10,d11,6) Q2(d12,d13,d14,8) Q2(d15,d16,d17,10)

__global__ __launch_bounds__(768, 3) void k_scanA3(const int* __restrict__ in_data,
        const float* __restrict__ GA, const float* __restrict__ xwA,
        const uint4* __restrict__ wpk, const float* __restrict__ bhh,
        unsigned* __restrict__ g1u, unsigned* hx, int* flags)
{
  __shared__ __align__(8) _Float16 h16[H1];      // full h, f16
  __shared__ float pg[96][3][9];                 // partials, padded
  __shared__ float xwb[2][3][96];                // xW double-buffer
  __shared__ int   indr[2][8];                   // staged in_data indices
  const int P = blockIdx.x;
  const int b = P & 63, hf = P >> 6;
  const int tid = threadIdx.x;
  const int r = tid % 96, s = tid / 96;
  const int k = s >> 1;                // partner-group 0..3 (0 = own)
  const int jq = hf ^ k;               // j-quarter this thread covers
  const int jb2 = (jq*2 + (s&1))*24;   // h2 base index into h16
  const int* ind_b = in_data + (size_t)b*TT*3;

  // weights: 18 named uint4 (72 VGPRs), loaded once
  const uint4* wsrc = wpk + (size_t)(hf*18)*768 + tid;
  LD18(0) LD18(1) LD18(2) LD18(3) LD18(4) LD18(5) LD18(6) LD18(7) LD18(8)
  LD18(9) LD18(10) LD18(11) LD18(12) LD18(13) LD18(14) LD18(15) LD18(16) LD18(17)

  // init h = 0
  if (tid < 192) ((unsigned*)h16)[tid] = 0u;
  // epilogue state (wave 0, lanes < 48): rows 2*tid, 2*tid+1 (local)
  float hreg0 = 0.f, hreg1 = 0.f, bn0 = 0.f, bn1 = 0.f;
  if (tid < 48){
    bn0 = bhh[768 + hf*96 + 2*tid];
    bn1 = bhh[768 + hf*96 + 2*tid + 1];
  }
  // prologue: xW for t=0 ; indices for t=1
  if (s >= 2 && (s & 1)){
    int g = (s-3) >> 1; int col = g*H1 + hf*96 + r;
    float acc = xwA[((size_t)b*JREP + 0)*G3 + col];
    #pragma unroll
    for (int k2 = 0; k2 < 6; ++k2){
      int v = ind_b[k2];
      acc += GA[((size_t)k2*256 + v)*G3 + col];
    }
    xwb[0][g][r] = acc;
  }
  if (s == 2 && r >= 48 && r < 54)
    indr[1][r-48] = ind_b[6 + (r-48)];
  const h2v* hh = (const h2v*)h16;
  unsigned* hxo = hx + ((size_t)(b*4 + hf)*2)*48;
  int* flgo = flags + (b*4 + hf)*32;
  __syncthreads();

  for (int t = 0; t < TS; ++t){
    // ---- phase 1 ----
    if (s < 2){
      float ar=0.f, az=0.f, an=0.f;
      DOTS12
      pg[r][0][s]=ar; pg[r][1][s]=az; pg[r][2][s]=an;
    } else if (!(s & 1)){
      if (r < 48){
        if (t > 0){
          int* fp = flags + (b*4 + jq)*32;
          while (__hip_atomic_load(fp, __ATOMIC_RELAXED, __HIP_MEMORY_SCOPE_AGENT) < t)
            __builtin_amdgcn_s_sleep(1);
          unsigned u = __hip_atomic_load(hx + ((size_t)(b*4 + jq)*2 + ((t-1)&1))*48 + r,
                                         __ATOMIC_RELAXED, __HIP_MEMORY_SCOPE_AGENT);
          ((unsigned*)h16)[jq*48 + r] = u;
        }
      } else if (s == 2 && r < 54){
        int t2 = t + 2;
        if (t2 < TS) indr[t2&1][r-48] = ind_b[6*t2 + (r-48)];
      }
    } else {
      int tp = t + 1;
      if (tp < TS){
        int g = (s-3) >> 1; int col = g*H1 + hf*96 + r;
        float acc = xwA[((size_t)b*JREP + tp/80)*G3 + col];
        int v0=indr[tp&1][0], v1=indr[tp&1][1], v2=indr[tp&1][2];
        int v3=indr[tp&1][3], v4=indr[tp&1][4], v5=indr[tp&1][5];
        acc += GA[((size_t)0*256 + v0)*G3 + col];
        acc += GA[((size_t)1*256 + v1)*G3 + col];
        acc += GA[((size_t)2*256 + v2)*G3 + col];
        acc += GA[((size_t)3*256 + v3)*G3 + col];
        acc += GA[((size_t)4*256 + v4)*G3 + col];
        acc += GA[((size_t)5*256 + v5)*G3 + col];
        xwb[tp&1][g][r] = acc;
      }
    }
    __syncthreads();
    // ---- phase 2 ----
    if (s >= 2){
      float ar=0.f, az=0.f, an=0.f;
      DOTS12
      pg[r][0][s]=ar; pg[r][1][s]=az; pg[r][2][s]=an;
    }
    __syncthreads();
    // ---- phase 3: epilogue (wave 0 lanes < 48) ----
    if (tid < 48){
      int r0 = 2*tid, r1 = 2*tid + 1;
      float R0 = xwb[t&1][0][r0], Z0 = xwb[t&1][1][r0], X0 = xwb[t&1][2][r0], G0 = bn0;
      float R1 = xwb[t&1][0][r1], Z1 = xwb[t&1][1][r1], X1 = xwb[t&1][2][r1], G1 = bn1;
      #pragma unroll
      for (int ss = 0; ss < 8; ++ss){
        R0 += pg[r0][0][ss]; Z0 += pg[r0][1][ss]; G0 += pg[r0][2][ss];
        R1 += pg[r1][0][ss]; Z1 += pg[r1][1][ss]; G1 += pg[r1][2][ss];
      }
      float rr0 = sigmf_(R0), zz0 = sigmf_(Z0);
      float nn0 = tanhf_(X0 + rr0*G0);
      float h0 = (1.f - zz0)*nn0 + zz0*hreg0; hreg0 = h0;
      float rr1 = sigmf_(R1), zz1 = sigmf_(Z1);
      float nn1 = tanhf_(X1 + rr1*G1);
      float h1 = (1.f - zz1)*nn1 + zz1*hreg1; hreg1 = h1;
      unsigned pack = (unsigned)__builtin_bit_cast(unsigned short, (_Float16)h0)
                    | ((unsigned)__builtin_bit_cast(unsigned short, (_Float16)h1) << 16);
      ((unsigned*)h16)[hf*48 + tid] = pack;
      g1u[((size_t)b*TS + t)*192 + hf*48 + tid] = pack;
      __hip_atomic_store(hxo + (size_t)(t&1)*48 + tid, pack,
                         __ATOMIC_RELAXED, __HIP_MEMORY_SCOPE_AGENT);
    }
    if (tid == 0)
      __hip_atomic_store(flgo, t+1, __ATOMIC_RELEASE, __HIP_MEMORY_SCOPE_AGENT);
    __syncthreads();
  }
}

// ---------------- xW_B = g1 @ gb_wih[:, :384].T + xWrepB ----------------
__global__ __launch_bounds__(256) void k_xwB(const _Float16* g1, const float* wih,
                                             const float* xwrB, float* xwB){
  __shared__ _Float16 gl[16*392];
  int bi = blockIdx.x; int b = bi/55; int t0 = (bi%55)*16; int tid = threadIdx.x;
  for (int idx = tid; idx < 16*H1; idx += 256){
    int tt = idx/H1, c = idx%H1;
    gl[tt*392+c] = g1[((size_t)b*TS + t0+tt)*H1 + c];
  }
  __syncthreads();
  int rr = tid>>4, tt = tid&15;
  int t = t0+tt;
  const float* xr = xwrB + ((size_t)(b*JREP) + t/80)*48;
  for (int rb = 0; rb < 3; ++rb){
    int r = rb*16 + rr;
    const float* wrow = wih + (size_t)r*512;
    float acc = 0.f;
    for (int c = 0; c < H1; ++c) acc += (float)gl[tt*392+c]*wrow[c];
    xwB[((size_t)b*TS + t)*48 + r] = acc + xr[r];
  }
}

// ---------------- GRU-B scan (tiny) ----------------
__global__ __launch_bounds__(64) void k_scanB(const float* xwB, const float* whh,
                                              const float* bhh, float* g2){
  __shared__ float wl[48*17];
  __shared__ float h2s[16];
  __shared__ float pre[32];
  __shared__ float xn[16], gn[16];
  int b = blockIdx.x, tid = threadIdx.x;
  for (int idx = tid; idx < 768; idx += 64) wl[(idx>>4)*17 + (idx&15)] = whh[idx];
  if (tid < 16) h2s[tid] = 0.f;
  float bn = (tid >= 32 && tid < 48) ? bhh[tid] : 0.f;
  __syncthreads();
  for (int t = 0; t < TS; ++t){
    if (tid < 48){
      float xw = xwB[((size_t)b*TS + t)*48 + tid];
      float gh = 0.f;
      for (int e = 0; e < 16; ++e) gh += wl[tid*17+e]*h2s[e];
      if (tid < 32) pre[tid] = xw + gh;
      else { xn[tid-32] = xw; gn[tid-32] = gh + bn; }
    }
    __syncthreads();
    if (tid < 16){
      float r = sigmf_(pre[tid]), z = sigmf_(pre[16+tid]);
      float n = tanhf_(xn[tid] + r*gn[tid]);
      float hn = (1.f - z)*n + z*h2s[tid];
      h2s[tid] = hn;
      g2[((size_t)b*TS + t)*16 + tid] = hn;
    }
    __syncthreads();
  }
}

// ---------------- mdense + output interleave ----------------
__global__ __launch_bounds__(256) void k_out(const float* g2, const int* targets, const float* T2,
    const float* m1w1, const float* m1w2, const float* m1b1, const float* m1b2,
    const float* m1f1, const float* m1f2,
    const float* m2w1, const float* m2w2, const float* m2b1, const float* m2b2,
    const float* m2f1, const float* m2f2, float* out)
{
  __shared__ float wA[256*17], wB[256*17], wC[256*17], wD[256*17];
  __shared__ float g2l[16*16];
  int bi = blockIdx.x; int b = bi/55; int t0 = (bi%55)*16; int c = threadIdx.x;
  for (int d = 0; d < 16; ++d){
    wA[c*17+d] = m1w1[c*16+d];  wB[c*17+d] = m1w2[c*16+d];
    wC[c*17+d] = m2w1[c*144+d]; wD[c*17+d] = m2w2[c*144+d];
  }
  { int tt = c>>4, d = c&15; g2l[c] = g2[((size_t)b*TS + t0+tt)*16 + d]; }
  __syncthreads();
  float b1a = m1b1[c], b2a = m1b2[c], f1a = m1f1[c], f2a = m1f2[c];
  float b1b = m2b1[c], b2b = m2b2[c], f1b = m2f1[c], f2b = m2f2[c];
  for (int tt = 0; tt < 16; ++tt){
    int t = t0+tt;
    float d1 = b1a, d2 = b2a, e1 = b1b, e2 = b2b;
    for (int d = 0; d < 16; ++d){
      float g = g2l[tt*16+d];
      d1 += g*wA[c*17+d]; d2 += g*wB[c*17+d];
      e1 += g*wC[c*17+d]; e2 += g*wD[c*17+d];
    }
    int v = targets[b*TT + 2*t];
    e1 += T2[v*256+c]; e2 += T2[65536 + v*256+c];
    float o1 = f1a*tanhf_(d1) + f2a*tanhf_(d2);
    float o2 = f1b*tanhf_(e1) + f2b*tanhf_(e2);
    size_t base = ((size_t)b*TS + t)*2*256;
    out[base + c]       = o1;
    out[base + 256 + c] = o2;
  }
}

extern "C" void kernel_launch(void* const* d_in, const int* in_sizes, int n_in,
                              void* d_out, int out_size, void* d_ws, size_t ws_size,
                              hipStream_t stream) {
  const int*   in_data = (const int*)  d_in[0];
  const float* feat    = (const float*)d_in[1];
  const int*   periods = (const int*)  d_in[2];
  const int*   targets = (const int*)  d_in[3];
  const float* embp    = (const float*)d_in[4];
  const float* embs    = (const float*)d_in[5];
  const float* c1w = (const float*)d_in[6];  const float* c1b = (const float*)d_in[7];
  const float* c2w = (const float*)d_in[8];  const float* c2b = (const float*)d_in[9];
  const float* f1w = (const float*)d_in[10]; const float* f1b = (const float*)d_in[11];
  const float* f2w = (const float*)d_in[12]; const float* f2b = (const float*)d_in[13];
  const float* ga_wih = (const float*)d_in[14]; const float* ga_whh = (const float*)d_in[15];
  const float* ga_bih = (const float*)d_in[16]; const float* ga_bhh = (const float*)d_in[17];
  const float* gb_wih = (const float*)d_in[18]; const float* gb_whh = (const float*)d_in[19];
  const float* gb_bih = (const float*)d_in[20]; const float* gb_bhh = (const float*)d_in[21];
  const float* m1w1 = (const float*)d_in[22]; const float* m1w2 = (const float*)d_in[23];
  const float* m1b1 = (const float*)d_in[24]; const float* m1b2 = (const float*)d_in[25];
  const float* m1f1 = (const float*)d_in[26]; const float* m1f2 = (const float*)d_in[27];
  const float* m2w1 = (const float*)d_in[28]; const float* m2w2 = (const float*)d_in[29];
  const float* m2b1 = (const float*)d_in[30]; const float* m2b2 = (const float*)d_in[31];
  const float* m2f1 = (const float*)d_in[32]; const float* m2f2 = (const float*)d_in[33];
  float* out = (float*)d_out;

  // workspace layout (floats)
  float* GA     = (float*)d_ws;                  // 6*256*1152     = 1,769,472
  float* xWrepA = GA     + 1769472;              // 704*1152       =   811,008
  float* xWrepB = xWrepA + 811008;               // 704*48         =    33,792
  float* fbuf   = xWrepB + 33792;                // 704*128        =    90,112
  float* xWB    = fbuf   + 90112;                // 56320*48       = 2,703,360
  float* g2buf  = xWB    + 2703360;              // 56320*16       =   901,120
  float* T2     = g2buf  + 901120;               // 2*256*256      =   131,072
  _Float16* Wpk = (_Float16*)(T2 + 131072);      // 442,368 halves
  unsigned* hx  = (unsigned*)(Wpk + 442368);     // 64*4*2*48 u32  =    24,576
  int*  flags   = (int*)(hx + 24576);            // 256*32 ints (128B padded)
  _Float16* g1  = (_Float16*)d_out;              // scratch inside output buffer (43.3MB < 115MB)

  hipMemsetAsync(flags, 0, 256*32*sizeof(int), stream);
  hipLaunchKernelGGL(k_frame, dim3(64), dim3(128), 0, stream,
                     feat, periods, embp, c1w, c1b, c2w, c2b, f1w, f1b, f2w, f2b, fbuf);
  hipLaunchKernelGGL(k_wpack3, dim3(1728), dim3(256), 0, stream, ga_whh, Wpk);
  hipLaunchKernelGGL(k_tables, dim3(108), dim3(256), 0, stream, ga_wih, embs, GA);
  hipLaunchKernelGGL(k_t2, dim3(8), dim3(256), 0, stream, m2w1, m2w2, embs, T2);
  hipLaunchKernelGGL(k_xwrepA, dim3(18), dim3(256), 0, stream, ga_wih, fbuf, ga_bih, ga_bhh, xWrepA);
  hipLaunchKernelGGL(k_xwrepB, dim3(64), dim3(256), 0, stream, gb_wih, fbuf, gb_bih, gb_bhh, xWrepB);
  hipLaunchKernelGGL(k_scanA3, dim3(256), dim3(768), 0, stream,
                     in_data, GA, xWrepA, (const uint4*)Wpk, ga_bhh,
                     (unsigned*)g1, hx, flags);
  hipLaunchKernelGGL(k_xwB, dim3(64*55), dim3(256), 0, stream, g1, gb_wih, xWrepB, xWB);
  hipLaunchKernelGGL(k_scanB, dim3(64), dim3(64), 0, stream, xWB, gb_whh, gb_bhh, g2buf);
  hipLaunchKernelGGL(k_out, dim3(64*55), dim3(256), 0, stream,
                     g2buf, targets, T2, m1w1, m1w2, m1b1, m1b2, m1f1, m1f2,
                     m2w1, m2w2, m2b1, m2b2, m2f1, m2f2, out);
}